// Round 9
// baseline (128.299 us; speedup 1.0000x reference)
//
#include <hip/hip_runtime.h>
#include <math.h>

// Problem constants
#define BATCH   8
#define LDIM    20
#define PIX     25600   // 160*160
#define PIX4    6400    // PIX/4 (float4 elements per image)
#define NLPAIRS 400     // N*L
#define NLR     800     // N*L*2

// P1 (projection) decomposition: wave-pair over 5 k-slices, in-register accum
#define KSPLIT  20
#define SLICE   (PIX4 / KSPLIT)     // 320 float4 per slice
#define WITER   (SLICE / 64)        // 5 iterations per slice per lane
#define NSETS   4                   // slice-sets; wave owns slices {set+4k}
#define NBLK    400                 // persistent grid (400 blocks x 256 thr)

// P3 (reconstruction)
#define RPIX    64                  // pixels per block tile
#define RKS     4                   // k-slices (one per wave)
#define RKLEN   (NLR / RKS)         // 200 k per wave

// Workspace layout (floats): part[4][800][8] | rot[800][8] | counters(2 u32)
#define PART_F  (NSETS * NLR * BATCH)   // 25600 floats
#define ROT_F   (NLR * BATCH)           // 6400 floats
#define CNT_OFF (PART_F + ROT_F)        // counter offset in floats

// Device-scope grid barrier (all NBLK blocks co-resident by construction).
__device__ __forceinline__ void grid_barrier(unsigned* cnt, unsigned target) {
    __syncthreads();
    if (threadIdx.x == 0) {
        __threadfence();                 // release our global writes
        atomicAdd(cnt, 1u);              // device-scope by default
        while (__hip_atomic_load(cnt, __ATOMIC_ACQUIRE,
                                 __HIP_MEMORY_SCOPE_AGENT) < target)
            __builtin_amdgcn_s_sleep(2);
    }
    __syncthreads();
}

// ---------------------------------------------------------------------------
// Fused persistent kernel: P1 projection -> bar -> P2 rotate -> bar -> P3 recon
// grid = 400 blocks x 256 threads (4 waves). ~70 VGPR, 31.6 KB LDS -> every
// block resident (>=2 blocks/CU guaranteed), so manual barriers cannot hang.
// ---------------------------------------------------------------------------
__global__ __launch_bounds__(256) void fused_kernel(
    const float* __restrict__ x,       // [8][25600]
    const float* __restrict__ basis,   // [800][25600]
    const float* __restrict__ angles,  // [8]
    float* __restrict__ out,           // [8][25600]
    float* __restrict__ ws)            // part | rot | counters
{
    __shared__ float rl[NLR * BATCH];            // 25.6 KB (P3 coeffs)
    __shared__ float red[RKS - 1][BATCH][RPIX];  // 6 KB   (P3 reduce)

    float* __restrict__ part = ws;
    float* __restrict__ rot  = ws + PART_F;
    unsigned* __restrict__ cnt = (unsigned*)(ws + CNT_OFF);

    const int tid  = threadIdx.x;
    const int lane = tid & 63;
    const int wv   = tid >> 6;                   // 0..3
    const int bid  = blockIdx.x;

    // ------------------ P1: projection ------------------
    {
        const int wid = bid * 4 + wv;            // 0..1599
        const int rp  = wid & (NLPAIRS - 1);     // row-pair 0..399 (400 = 16*25; use %)
        const int rpm = wid % NLPAIRS;
        const int set = wid / NLPAIRS;           // 0..3
        (void)rp;
        const int r0 = rpm * 2;

        const float4* __restrict__ b0 = (const float4*)(basis + (size_t)r0 * PIX);
        const float4* __restrict__ b1 = (const float4*)(basis + (size_t)(r0 + 1) * PIX);
        const float4* __restrict__ x4 = (const float4*)x;

        float acc0[BATCH], acc1[BATCH];
        #pragma unroll
        for (int b = 0; b < BATCH; ++b) { acc0[b] = 0.0f; acc1[b] = 0.0f; }

        // 5 slices (set, set+4, ..., set+16), accumulate in-register
        #pragma unroll
        for (int k = 0; k < 5; ++k) {
            const int kb = (set + 4 * k) * SLICE;
            #pragma unroll
            for (int it = 0; it < WITER; ++it) {
                const int i = kb + it * 64 + lane;
                float4 v0 = b0[i];
                float4 v1 = b1[i];
                #pragma unroll
                for (int b = 0; b < BATCH; ++b) {
                    float4 xv = x4[(size_t)b * PIX4 + i];
                    acc0[b] = fmaf(v0.x, xv.x, acc0[b]);
                    acc0[b] = fmaf(v0.y, xv.y, acc0[b]);
                    acc0[b] = fmaf(v0.z, xv.z, acc0[b]);
                    acc0[b] = fmaf(v0.w, xv.w, acc0[b]);
                    acc1[b] = fmaf(v1.x, xv.x, acc1[b]);
                    acc1[b] = fmaf(v1.y, xv.y, acc1[b]);
                    acc1[b] = fmaf(v1.z, xv.z, acc1[b]);
                    acc1[b] = fmaf(v1.w, xv.w, acc1[b]);
                }
            }
        }

        // Intra-wave butterfly reduction (16 values -> lane 0), once per wave
        #pragma unroll
        for (int b = 0; b < BATCH; ++b) {
            #pragma unroll
            for (int off = 32; off > 0; off >>= 1) {
                acc0[b] += __shfl_down(acc0[b], off);
                acc1[b] += __shfl_down(acc1[b], off);
            }
        }

        if (lane == 0) {
            float* __restrict__ dst = part + ((size_t)set * NLR + r0) * BATCH;
            #pragma unroll
            for (int b = 0; b < BATCH; ++b) {
                dst[b]         = acc0[b];
                dst[BATCH + b] = acc1[b];
            }
        }
    }

    grid_barrier(&cnt[0], NBLK);

    // ------------------ P2: partial-sum + rotation (blocks 0..24) ------------------
    {
        const int idx = bid * 256 + tid;         // 0..102399; work < 6400
        if (idx < NLR * BATCH) {
            const int nlr = idx >> 3;
            const int b   = idx & 7;
            float self = 0.0f, other = 0.0f;
            #pragma unroll
            for (int s = 0; s < NSETS; ++s) {
                self  += part[((size_t)s * NLR + nlr) * BATCH + b];
                other += part[((size_t)s * NLR + (nlr ^ 1)) * BATCH + b];
            }
            const int l = (nlr >> 1) % LDIM;
            float ca, sa;
            __sincosf(angles[b] * (float)l, &sa, &ca);
            rot[idx] = (nlr & 1) == 0 ? fmaf(self, ca, other * sa)
                                      : fmaf(self, ca, -other * sa);
        }
    }

    grid_barrier(&cnt[1], NBLK);

    // ------------------ P3: reconstruction ------------------
    {
        // Stage rotated coeffs to LDS
        for (int idx = tid; idx < NLR * BATCH; idx += 256)
            rl[idx] = rot[idx];
        __syncthreads();

        const int pix = bid * RPIX + lane;

        float acc[BATCH];
        #pragma unroll
        for (int b = 0; b < BATCH; ++b) acc[b] = 0.0f;

        const float* __restrict__ bp = basis + (size_t)(wv * RKLEN) * PIX + pix;
        const float* __restrict__ rp2 = &rl[(wv * RKLEN) * BATCH];

        #pragma unroll 10
        for (int k = 0; k < RKLEN; ++k) {
            float bv = bp[(size_t)k * PIX];
            float4 v0 = *(const float4*)&rp2[k * BATCH];
            float4 v1 = *(const float4*)&rp2[k * BATCH + 4];
            acc[0] = fmaf(bv, v0.x, acc[0]);
            acc[1] = fmaf(bv, v0.y, acc[1]);
            acc[2] = fmaf(bv, v0.z, acc[2]);
            acc[3] = fmaf(bv, v0.w, acc[3]);
            acc[4] = fmaf(bv, v1.x, acc[4]);
            acc[5] = fmaf(bv, v1.y, acc[5]);
            acc[6] = fmaf(bv, v1.z, acc[6]);
            acc[7] = fmaf(bv, v1.w, acc[7]);
        }

        if (wv > 0) {
            #pragma unroll
            for (int b = 0; b < BATCH; ++b)
                red[wv - 1][b][lane] = acc[b];
        }
        __syncthreads();

        if (wv == 0) {
            #pragma unroll
            for (int w = 0; w < RKS - 1; ++w)
                #pragma unroll
                for (int b = 0; b < BATCH; ++b)
                    acc[b] += red[w][b][lane];
            #pragma unroll
            for (int b = 0; b < BATCH; ++b)
                out[(size_t)b * PIX + pix] = acc[b];
        }
    }
}

extern "C" void kernel_launch(void* const* d_in, const int* in_sizes, int n_in,
                              void* d_out, int out_size, void* d_ws, size_t ws_size,
                              hipStream_t stream) {
    (void)in_sizes; (void)n_in; (void)ws_size; (void)out_size;

    const float* x      = (const float*)d_in[0];   // [8][1][160][160]
    const float* basis  = (const float*)d_in[1];   // [20][20][2][160][160]
    const float* angles = (const float*)d_in[2];   // [8]
    float* out = (float*)d_out;                    // [8][1][160][160]
    float* ws  = (float*)d_ws;

    // Zero the two barrier counters (poisoned by harness). 8 bytes only.
    hipMemsetAsync((char*)d_ws + CNT_OFF * sizeof(float), 0, 2 * sizeof(unsigned), stream);

    fused_kernel<<<dim3(NBLK), dim3(256), 0, stream>>>(x, basis, angles, out, ws);
}

// Round 10
// 42.497 us; speedup vs baseline: 3.0190x; 3.0190x over previous
//
#include <hip/hip_runtime.h>
#include <math.h>

// Problem constants
#define BATCH   8
#define LDIM    20
#define PIX     25600   // 160*160
#define NLPAIRS 400     // N*L
#define NLR     800     // N*L*2

// Projection decomposition: lane owns 4 pixels, wave owns 8 rows.
#define PPB     256                 // pixels per block (64 lanes * 4)
#define NPX     (PIX / PPB)         // 100 pixel-slices
#define RSPLIT  25                  // row-groups per pixel-slice (32 rows each)
// grid = (100, 25) x 256 thr (4 waves); wave w handles rows y*32 + w*8 .. +8

// Reconstruction
#define RPIX    64                  // pixels per recon block
#define RKS     8                   // k-slices (one per wave, 512 threads)
#define RKLEN   (NLR / RKS)         // 100 k per wave

// ---------------------------------------------------------------------------
// Kernel A: projection, recon-style streaming.
// Lane: x[8 batch][4 pix] in regs (loaded once), 8 basis-row dwordx4 loads,
// 256 FMA, then a 6-level register reduce-scatter (63 shfl_xor) leaving lane
// l with the final partial for (r = l>>3, b = l&7). One coalesced store.
// Basis read EXACTLY once chip-wide (82 MB); x only 80 MB L2; no LDS.
// ---------------------------------------------------------------------------
__global__ __launch_bounds__(256) void proj_kernel(
    const float* __restrict__ x,       // [8][25600]
    const float* __restrict__ basis,   // [800][25600]
    float* __restrict__ part)          // [NPX][800][8]
{
    const int tid   = threadIdx.x;
    const int lane  = tid & 63;
    const int wv    = tid >> 6;                       // 0..3
    const int p     = blockIdx.x;                     // pixel slice 0..99
    const int rbase = blockIdx.y * 32 + wv * 8;       // this wave's 8 rows
    const int px    = p * PPB + lane * 4;             // lane's first pixel

    // x in registers: 8 batch x float4 = 32 VGPR, loaded once
    float4 xv[BATCH];
    #pragma unroll
    for (int b = 0; b < BATCH; ++b)
        xv[b] = *(const float4*)(x + (size_t)b * PIX + px);

    // 8 basis rows, independent streams
    float4 bv[8];
    #pragma unroll
    for (int r = 0; r < 8; ++r)
        bv[r] = *(const float4*)(basis + (size_t)(rbase + r) * PIX + px);

    // v[i] = partial dot for (r = i>>3, b = i&7) over this lane's 4 pixels
    float v[64];
    #pragma unroll
    for (int r = 0; r < 8; ++r)
        #pragma unroll
        for (int b = 0; b < BATCH; ++b)
            v[r * 8 + b] = fmaf(bv[r].w, xv[b].w,
                           fmaf(bv[r].z, xv[b].z,
                           fmaf(bv[r].y, xv[b].y, bv[r].x * xv[b].x)));

    // Register reduce-scatter: 6 xor-levels; after level k, lane holds values
    // for indices i == (lane mod 2^(k+1)) (mod 2^(k+1)), compacted in v[0..].
    // Ends with lane l holding the full 64-lane sum for index i == l.
    #pragma unroll
    for (int k = 0; k < 6; ++k) {
        const int m  = 1 << k;
        const int kb = (lane >> k) & 1;
        const int n  = 64 >> k;
        #pragma unroll
        for (int j = 0; j < 32; ++j) {         // only j < n/2 are live
            if (j < n / 2) {
                float a    = v[2 * j];
                float c    = v[2 * j + 1];
                float send = kb ? a : c;       // cndmask, static reg indices
                float keep = kb ? c : a;
                v[j] = keep + __shfl_xor(send, m);
            }
        }
    }

    // lane l owns (rbase + (l>>3), b = l&7): one coalesced 256B store/wave
    part[(size_t)p * (NLR * BATCH) + blockIdx.y * 256 + wv * 64 + lane] = v[0];
}

// ---------------------------------------------------------------------------
// Kernel B: partial-sum over 100 pixel-slices + rotation.
// 6400 threads = one per (nlr, b); conjugate partner fetched via shfl_xor.
// ---------------------------------------------------------------------------
__global__ __launch_bounds__(256) void rotate_kernel(
    const float* __restrict__ part,    // [NPX][800][8]
    const float* __restrict__ angles,  // [8]
    float* __restrict__ rot)           // [800][8]
{
    const int idx = blockIdx.x * 256 + threadIdx.x;   // 0..6399
    const int nlr = idx >> 3;
    const int b   = idx & 7;

    float self = 0.0f;
    for (int p = 0; p < NPX; ++p)
        self += part[(size_t)p * (NLR * BATCH) + idx];

    // (nlr ^ 1) flips bit 3 of idx; partner is in the same wave.
    float other = __shfl_xor(self, 8);

    const int l = (nlr >> 1) % LDIM;
    float ca, sa;
    __sincosf(angles[b] * (float)l, &sa, &ca);
    // a = c0*ca + c1*sa ; b = c1*ca - c0*sa
    rot[idx] = (nlr & 1) == 0 ? fmaf(self, ca, other * sa)
                              : fmaf(self, ca, -other * sa);
}

// ---------------------------------------------------------------------------
// Kernel C: reconstruction (unchanged from round 4; near its traffic floor).
// grid = 400 blocks of 512 threads (8 waves). Each wave owns a 100-k slice
// over 64 pixels; LDS tree-reduce across waves; direct coalesced stores.
// ---------------------------------------------------------------------------
__global__ __launch_bounds__(512) void recon_kernel(
    const float* __restrict__ basis,   // [800][25600]
    const float* __restrict__ rot,     // [800][8]
    float* __restrict__ out)           // [8][25600]
{
    __shared__ float rl[NLR * BATCH];            // 25.6 KB rotated coeffs
    __shared__ float red[RKS - 1][BATCH][RPIX];  // 14.3 KB, lane-consecutive

    const int tid = threadIdx.x;

    for (int idx = tid; idx < NLR * BATCH; idx += 512)
        rl[idx] = rot[idx];
    __syncthreads();

    const int lane = tid & 63;
    const int ks   = tid >> 6;                 // wave = k-slice
    const int pix  = blockIdx.x * RPIX + lane;

    float acc[BATCH];
    #pragma unroll
    for (int b = 0; b < BATCH; ++b) acc[b] = 0.0f;

    const float* __restrict__ bp = basis + (size_t)(ks * RKLEN) * PIX + pix;
    const float* __restrict__ rp = &rl[(ks * RKLEN) * BATCH];

    #pragma unroll 10
    for (int k = 0; k < RKLEN; ++k) {
        float bvv = bp[(size_t)k * PIX];
        float4 v0 = *(const float4*)&rp[k * BATCH];
        float4 v1 = *(const float4*)&rp[k * BATCH + 4];
        acc[0] = fmaf(bvv, v0.x, acc[0]);
        acc[1] = fmaf(bvv, v0.y, acc[1]);
        acc[2] = fmaf(bvv, v0.z, acc[2]);
        acc[3] = fmaf(bvv, v0.w, acc[3]);
        acc[4] = fmaf(bvv, v1.x, acc[4]);
        acc[5] = fmaf(bvv, v1.y, acc[5]);
        acc[6] = fmaf(bvv, v1.z, acc[6]);
        acc[7] = fmaf(bvv, v1.w, acc[7]);
    }

    if (ks > 0) {
        #pragma unroll
        for (int b = 0; b < BATCH; ++b)
            red[ks - 1][b][lane] = acc[b];
    }
    __syncthreads();

    if (ks == 0) {
        #pragma unroll
        for (int w = 0; w < RKS - 1; ++w)
            #pragma unroll
            for (int b = 0; b < BATCH; ++b)
                acc[b] += red[w][b][lane];
        #pragma unroll
        for (int b = 0; b < BATCH; ++b)
            out[(size_t)b * PIX + pix] = acc[b];
    }
}

extern "C" void kernel_launch(void* const* d_in, const int* in_sizes, int n_in,
                              void* d_out, int out_size, void* d_ws, size_t ws_size,
                              hipStream_t stream) {
    (void)in_sizes; (void)n_in; (void)ws_size; (void)out_size;

    const float* x      = (const float*)d_in[0];   // [8][1][160][160]
    const float* basis  = (const float*)d_in[1];   // [20][20][2][160][160]
    const float* angles = (const float*)d_in[2];   // [8]
    float* out  = (float*)d_out;                   // [8][1][160][160]
    float* part = (float*)d_ws;                    // [100][800][8] = 2.56 MB
    float* rot  = part + (size_t)NPX * NLR * BATCH;     // [800][8]

    proj_kernel<<<dim3(NPX, RSPLIT), dim3(256), 0, stream>>>(x, basis, part);
    rotate_kernel<<<dim3(NLR * BATCH / 256), dim3(256), 0, stream>>>(part, angles, rot);
    recon_kernel<<<dim3(PIX / RPIX), dim3(512), 0, stream>>>(basis, rot, out);
}